// Round 11
// baseline (391.289 us; speedup 1.0000x reference)
//
#include <hip/hip_runtime.h>
#include <math.h>

#define N_NODES 50000
#define N_EDGES 800000
#define N_GRAPHS 512
#define IN_DIM 128
#define HID_DIM 256
#define EMB_DIM 128
#define EPS 1e-5f
#define ELLW 64
#define NGROUP 8
#define GROUPN 6250
#define BLK_PER_GROUP 256
#define EPB ((N_EDGES + BLK_PER_GROUP - 1) / BLK_PER_GROUP)
#define F2B_N (N_NODES * IN_DIM / 4)
#define F2B_BLOCKS ((F2B_N + 255) / 256)
#define TW1_BLOCKS ((HID_DIM * IN_DIM + 255) / 256)
#define DINV_BLOCKS ((N_NODES + 255) / 256)
#define GEMM_BLOCKS ((N_NODES + 127) / 128)   // 391, 128 rows per block

typedef __attribute__((ext_vector_type(8))) short bf16x8;
typedef __attribute__((ext_vector_type(4))) float f32x4;

static __device__ __forceinline__ unsigned short f2b(float f) {
    unsigned u = __float_as_uint(f);
    return (unsigned short)((u + 0x7fffu + ((u >> 16) & 1u)) >> 16);
}
static __device__ __forceinline__ float b2f(unsigned short h) {
    return __uint_as_float(((unsigned)h) << 16);
}

// ---------- ELL build, XCD-partitioned by dst range (blockIdx%8 -> XCD heuristic) ----------
__global__ void __launch_bounds__(256) scatter_xcd(const int* __restrict__ src,
                                                   const int* __restrict__ dst,
                                                   int* __restrict__ fill,
                                                   int* __restrict__ col) {
    int b = blockIdx.x;
    int g = b & 7;
    int bs = b >> 3;
    int lo = g * GROUPN;
    int hi = lo + GROUPN;
    int e_end = min((bs + 1) * EPB, N_EDGES);
    for (int e = bs * EPB + threadIdx.x; e < e_end; e += 256) {
        int d = dst[e];
        if (d >= lo && d < hi) {
            int pos = atomicAdd(&fill[d], 1);
            pos = min(pos, ELLW - 1);
            col[(d << 6) + pos] = src[e];
        }
    }
}

// ---------- fused conversions + dinv ----------
__global__ void convert_kernel(const float* __restrict__ x, unsigned short* __restrict__ xbf,
                               const float* __restrict__ W1, unsigned short* __restrict__ W1t,
                               const int* __restrict__ fill, float* __restrict__ dinv) {
    int b = blockIdx.x;
    if (b < F2B_BLOCKS) {
        int i = b * 256 + threadIdx.x;
        if (i < F2B_N) {
            float4 v = ((const float4*)x)[i];
            ushort4 o;
            o.x = f2b(v.x); o.y = f2b(v.y); o.z = f2b(v.z); o.w = f2b(v.w);
            ((ushort4*)xbf)[i] = o;
        }
    } else if (b < F2B_BLOCKS + TW1_BLOCKS) {
        int j = (b - F2B_BLOCKS) * 256 + threadIdx.x;
        if (j < HID_DIM * IN_DIM) {
            int n = j >> 7;
            int k = j & 127;
            W1t[j] = f2b(W1[k * HID_DIM + n]);
        }
    } else {
        int v = (b - F2B_BLOCKS - TW1_BLOCKS) * 256 + threadIdx.x;
        if (v < N_NODES) dinv[v] = rsqrtf((float)(min(fill[v], ELLW) + 1));
    }
}

// ---------- wave-per-node aggregation over ELL, quarter-wave 16B row gathers ----------
static __device__ __forceinline__ void acc8(float* acc, uint4 r, float w) {
    const unsigned* u = (const unsigned*)&r;
#pragma unroll
    for (int k = 0; k < 4; ++k) {
        float lo = __uint_as_float((u[k] & 0xFFFFu) << 16);
        float hi = __uint_as_float(u[k] & 0xFFFF0000u);
        acc[2 * k]     += w * lo;
        acc[2 * k + 1] += w * hi;
    }
}

template <bool RELU, bool OUT_BF, bool BIAS>
__global__ void __launch_bounds__(256) aggw_kernel(const unsigned short* __restrict__ h,
                                                   const float* __restrict__ dinv,
                                                   const int* __restrict__ deg,
                                                   const int* __restrict__ col,
                                                   const float* __restrict__ bias,
                                                   void* __restrict__ y) {
    int tid = threadIdx.x;
    int lane = tid & 63;
    int wid = tid >> 6;
    int v = blockIdx.x * 4 + wid;
    int g = lane >> 4;
    int p = lane & 15;

    int beg = v << 6;
    int end = beg + min(deg[v], ELLW);
    float acc[8] = {};

    for (int e = beg; e < end; e += 16) {
        int i0 = e + g, i1 = e + 4 + g, i2 = e + 8 + g, i3 = e + 12 + g;
        int c0 = min(i0, end - 1), c1 = min(i1, end - 1);
        int c2 = min(i2, end - 1), c3 = min(i3, end - 1);
        int u0 = col[c0], u1 = col[c1], u2 = col[c2], u3 = col[c3];
        float w0 = (i0 < end) ? dinv[u0] : 0.f;
        float w1 = (i1 < end) ? dinv[u1] : 0.f;
        float w2 = (i2 < end) ? dinv[u2] : 0.f;
        float w3 = (i3 < end) ? dinv[u3] : 0.f;
        uint4 d0 = *(const uint4*)(h + (size_t)u0 * 128 + p * 8);
        uint4 d1 = *(const uint4*)(h + (size_t)u1 * 128 + p * 8);
        uint4 d2 = *(const uint4*)(h + (size_t)u2 * 128 + p * 8);
        uint4 d3 = *(const uint4*)(h + (size_t)u3 * 128 + p * 8);
        acc8(acc, d0, w0);
        acc8(acc, d1, w1);
        acc8(acc, d2, w2);
        acc8(acc, d3, w3);
    }

#pragma unroll
    for (int k = 0; k < 8; ++k) {
        float a = acc[k];
        a += __shfl_xor(a, 16, 64);
        a += __shfl_xor(a, 32, 64);
        acc[k] = a;
    }

    if (g == 0) {
        uint4 selfr = *(const uint4*)(h + (size_t)v * 128 + p * 8);
        const unsigned* su = (const unsigned*)&selfr;
        float dv = dinv[v];
        float dv2 = dv * dv;
        float o[8];
#pragma unroll
        for (int k = 0; k < 4; ++k) {
            float lo = __uint_as_float((su[k] & 0xFFFFu) << 16);
            float hi = __uint_as_float(su[k] & 0xFFFF0000u);
            o[2 * k]     = dv * acc[2 * k]     + lo * dv2;
            o[2 * k + 1] = dv * acc[2 * k + 1] + hi * dv2;
        }
        if (BIAS) {
            float4 bv0 = *(const float4*)&bias[p * 8];
            float4 bv1 = *(const float4*)&bias[p * 8 + 4];
            o[0] += bv0.x; o[1] += bv0.y; o[2] += bv0.z; o[3] += bv0.w;
            o[4] += bv1.x; o[5] += bv1.y; o[6] += bv1.z; o[7] += bv1.w;
        }
        if (RELU) {
#pragma unroll
            for (int k = 0; k < 8; ++k) o[k] = fmaxf(o[k], 0.f);
        }
        if (OUT_BF) {
            uint4 packed;
            unsigned* pu = (unsigned*)&packed;
#pragma unroll
            for (int k = 0; k < 4; ++k)
                pu[k] = (unsigned)f2b(o[2 * k]) | ((unsigned)f2b(o[2 * k + 1]) << 16);
            *(uint4*)((unsigned short*)y + (size_t)v * 128 + p * 8) = packed;
        } else {
            float* yf = (float*)y + (size_t)v * 128 + p * 8;
            *(float4*)yf = make_float4(o[0], o[1], o[2], o[3]);
            *(float4*)(yf + 4) = make_float4(o[4], o[5], o[6], o[7]);
        }
    }
}

// ---------- weight-resident MFMA GEMM: C[M,N] = maybe_relu(A[M,K] @ Bt[N,K]^T + bias) ----------
// Whole Bt (64KB bf16) staged once into LDS in fragment-swizzled order -> conflict-free
// ds_read_b128; A fragments loaded directly from global (k-contiguous 16B = native A layout).
// No barriers in the compute loop. Wave owns 32 rows (2 m-frags); n-tiles in pairs (4 chains).
template <bool RELU, bool STATS, int N, int K>
__global__ void __launch_bounds__(256) gemm_wres(const unsigned short* __restrict__ A,
                                                 const unsigned short* __restrict__ Bt,
                                                 const float* __restrict__ bias,
                                                 unsigned short* __restrict__ C,
                                                 float* __restrict__ sum,
                                                 float* __restrict__ sumsq,
                                                 int M) {
    constexpr int NT = N / 16;
    constexpr int KT = K / 32;
    __shared__ unsigned short Blds[N * K];   // 64 KB for both instantiations
    int tid = threadIdx.x;
    int lane = tid & 63;
    int w = tid >> 6;
    int l15 = lane & 15, q = lane >> 4;

    // stage B, swizzled to fragment order: chunk c = frag*64 + lane -> 16B
    for (int c = tid; c < N * K / 8; c += 256) {
        int f = c >> 6;
        int l = c & 63;
        int nt = f / KT, kk = f - nt * KT;
        int sl15 = l & 15, sq = l >> 4;
        uint4 v = *(const uint4*)(Bt + (size_t)(nt * 16 + sl15) * K + kk * 32 + sq * 8);
        *(uint4*)&Blds[(size_t)c * 8] = v;
    }
    __syncthreads();

    int mbase = blockIdx.x * 128 + w * 32;
    int ar0 = mbase + l15;
    int ar1 = mbase + 16 + l15;
    int ac0 = min(ar0, M - 1);
    int ac1 = min(ar1, M - 1);

    uint4 areg0[KT], areg1[KT];
#pragma unroll
    for (int kk = 0; kk < KT; ++kk) {
        areg0[kk] = *(const uint4*)(A + (size_t)ac0 * K + kk * 32 + q * 8);
        areg1[kk] = *(const uint4*)(A + (size_t)ac1 * K + kk * 32 + q * 8);
    }

    for (int nt = 0; nt < NT; nt += 2) {
        f32x4 acc00 = {}, acc01 = {}, acc10 = {}, acc11 = {};
#pragma unroll
        for (int kk = 0; kk < KT; ++kk) {
            bf16x8 b0 = *(const bf16x8*)&Blds[(size_t)(((nt + 0) * KT + kk) * 64 + lane) * 8];
            bf16x8 b1 = *(const bf16x8*)&Blds[(size_t)(((nt + 1) * KT + kk) * 64 + lane) * 8];
            bf16x8 a0 = *(const bf16x8*)&areg0[kk];
            bf16x8 a1 = *(const bf16x8*)&areg1[kk];
            acc00 = __builtin_amdgcn_mfma_f32_16x16x32_bf16(a0, b0, acc00, 0, 0, 0);
            acc10 = __builtin_amdgcn_mfma_f32_16x16x32_bf16(a1, b0, acc10, 0, 0, 0);
            acc01 = __builtin_amdgcn_mfma_f32_16x16x32_bf16(a0, b1, acc01, 0, 0, 0);
            acc11 = __builtin_amdgcn_mfma_f32_16x16x32_bf16(a1, b1, acc11, 0, 0, 0);
        }
#pragma unroll
        for (int ni = 0; ni < 2; ++ni) {
            int colc = (nt + ni) * 16 + l15;
            float bv = bias ? bias[colc] : 0.f;
            float s = 0.f, sq2 = 0.f;
#pragma unroll
            for (int mi = 0; mi < 2; ++mi) {
                const f32x4& acc = (mi == 0) ? (ni == 0 ? acc00 : acc01)
                                             : (ni == 0 ? acc10 : acc11);
                int rbase = mbase + mi * 16 + q * 4;
#pragma unroll
                for (int r = 0; r < 4; ++r) {
                    int row = rbase + r;
                    bool ok = row < M;
                    float vv = acc[r] + bv;
                    if (RELU) vv = fmaxf(vv, 0.f);
                    unsigned short us = f2b(vv);
                    if (ok) C[(size_t)row * N + colc] = us;
                    if (STATS) {
                        float xr = ok ? b2f(us) : 0.f;
                        s += xr;
                        sq2 += xr * xr;
                    }
                }
            }
            if (STATS) {
                s += __shfl_xor(s, 16, 64);  s += __shfl_xor(s, 32, 64);
                sq2 += __shfl_xor(sq2, 16, 64); sq2 += __shfl_xor(sq2, 32, 64);
                if (q == 0) {
                    atomicAdd(&sum[colc], s);
                    atomicAdd(&sumsq[colc], sq2);
                }
            }
        }
    }
}

// ---------- fast per-channel sum/sumsq (for fp32 y2) ----------
template <int C, bool BF>
__global__ void __launch_bounds__(256) stats_fast(const void* __restrict__ yv,
                                                  float* __restrict__ sum,
                                                  float* __restrict__ sumsq) {
    constexpr int VEC = BF ? 8 : 4;
    constexpr int NCHUNK = C / VEC;
    constexpr int ROWS = 256 / NCHUNK;
    constexpr int STRIDE = 256 * ROWS;
    __shared__ float sp[256 * VEC];
    __shared__ float qp[256 * VEC];
    int t = threadIdx.x;
    int j = t & (NCHUNK - 1);
    float s[VEC], q[VEC];
#pragma unroll
    for (int k = 0; k < VEC; ++k) { s[k] = 0.f; q[k] = 0.f; }

    const char* base = (const char*)yv + (size_t)j * 16;
    auto body = [&](int v) {
        uint4 raw = *(const uint4*)(base + (size_t)v * (C * (BF ? 2 : 4)));
        float x[VEC];
        if (BF) {
            const unsigned* u = (const unsigned*)&raw;
#pragma unroll
            for (int k = 0; k < 4; ++k) {
                x[2 * k]     = __uint_as_float((u[k] & 0xFFFFu) << 16);
                x[2 * k + 1] = __uint_as_float(u[k] & 0xFFFF0000u);
            }
        } else {
            const float* f = (const float*)&raw;
#pragma unroll
            for (int k = 0; k < VEC; ++k) x[k] = f[k];
        }
#pragma unroll
        for (int k = 0; k < VEC; ++k) { s[k] += x[k]; q[k] += x[k] * x[k]; }
    };

    int v = blockIdx.x * ROWS + (t >> 5);
    for (; v + 3 * STRIDE < N_NODES; v += 4 * STRIDE) {
        body(v); body(v + STRIDE); body(v + 2 * STRIDE); body(v + 3 * STRIDE);
    }
    for (; v < N_NODES; v += STRIDE) body(v);

#pragma unroll
    for (int k = 0; k < VEC; ++k) { sp[t * VEC + k] = s[k]; qp[t * VEC + k] = q[k]; }
    __syncthreads();
    if (t < C) {
        float ss = 0.f, qq = 0.f;
#pragma unroll
        for (int rr = 0; rr < ROWS; ++rr) {
            ss += sp[rr * (NCHUNK * VEC) + t];
            qq += qp[rr * (NCHUNK * VEC) + t];
        }
        atomicAdd(&sum[t], ss);
        atomicAdd(&sumsq[t], qq);
    }
}

// ---------- fold BN1 into W2 ----------
__global__ void prep2_kernel(const float* __restrict__ sum1, const float* __restrict__ sumsq1,
                             const float* __restrict__ gamma1, const float* __restrict__ beta1,
                             const float* __restrict__ W2, unsigned short* __restrict__ W2pt,
                             float* __restrict__ bc2) {
    __shared__ float a1s[HID_DIM], s1s[HID_DIM];
    int t = threadIdx.x;
    {
        float m = sum1[t] * (1.f / N_NODES);
        float var = sumsq1[t] * (1.f / N_NODES) - m * m;
        float a = gamma1[t] * rsqrtf(var + EPS);
        a1s[t] = a;
        s1s[t] = beta1[t] - m * a;
    }
    __syncthreads();
    if (t < EMB_DIM) {
        float bacc = 0.f;
        for (int k = 0; k < HID_DIM; ++k) {
            float w = W2[k * EMB_DIM + t];
            W2pt[t * HID_DIM + k] = f2b(a1s[k] * w);
            bacc += s1s[k] * w;
        }
        bc2[t] = bacc;
    }
}

// ---------- segmented max per graph (batch sorted), BN2 fold computed in-block ----------
__global__ void __launch_bounds__(128) segmax_kernel(const float* __restrict__ y,
                                                     const float* __restrict__ sum2,
                                                     const float* __restrict__ sumsq2,
                                                     const float* __restrict__ gamma2,
                                                     const float* __restrict__ beta2,
                                                     const int* __restrict__ batch,
                                                     float* __restrict__ out) {
    __shared__ int sh[2];
    int g = blockIdx.x;
    int c = threadIdx.x;
    float mch = sum2[c] * (1.f / N_NODES);
    float var = sumsq2[c] * (1.f / N_NODES) - mch * mch;
    float ac = gamma2[c] * rsqrtf(var + EPS);
    float sc = beta2[c] - mch * ac;
    if (threadIdx.x == 0) {
        int lo = 0, hi = N_NODES;
        while (lo < hi) { int mid = (lo + hi) >> 1; if (batch[mid] < g) lo = mid + 1; else hi = mid; }
        sh[0] = lo;
        hi = N_NODES;
        while (lo < hi) { int mid = (lo + hi) >> 1; if (batch[mid] < g + 1) lo = mid + 1; else hi = mid; }
        sh[1] = lo;
    }
    __syncthreads();
    int beg = sh[0], end = sh[1];
    float m = -INFINITY;
    for (int v = beg; v < end; ++v) {
        m = fmaxf(m, fmaf(ac, y[(size_t)v * EMB_DIM + c], sc));
    }
    out[(size_t)g * EMB_DIM + c] = m;
}

extern "C" void kernel_launch(void* const* d_in, const int* in_sizes, int n_in,
                              void* d_out, int out_size, void* d_ws, size_t ws_size,
                              hipStream_t stream) {
    const float* x      = (const float*)d_in[0];
    const int*   ei     = (const int*)d_in[1];
    const int*   batch  = (const int*)d_in[2];
    const float* W1     = (const float*)d_in[3];
    const float* b1     = (const float*)d_in[4];
    const float* gamma1 = (const float*)d_in[5];
    const float* beta1  = (const float*)d_in[6];
    const float* W2     = (const float*)d_in[7];
    const float* b2     = (const float*)d_in[8];
    const float* gamma2 = (const float*)d_in[9];
    const float* beta2  = (const float*)d_in[10];
    float* out = (float*)d_out;

    char* ws = (char*)d_ws;
    size_t off = 0;
    auto alloc = [&](size_t bytes) -> char* {
        char* p = ws + off;
        off = (off + bytes + 255) & ~(size_t)255;
        return p;
    };
    int*   fill   = (int*)alloc((size_t)N_NODES * 4);
    float* stats  = (float*)alloc(1024 * 4);
    size_t zbytes = off;
    int*   col    = (int*)alloc((size_t)N_NODES * ELLW * 4);
    float* dinv   = (float*)alloc((size_t)N_NODES * 4);
    float* bc2    = (float*)alloc((size_t)EMB_DIM * 4);
    unsigned short* W1t  = (unsigned short*)alloc((size_t)HID_DIM * IN_DIM * 2);
    unsigned short* W2pt = (unsigned short*)alloc((size_t)HID_DIM * EMB_DIM * 2);
    unsigned short* xbf  = (unsigned short*)alloc((size_t)N_NODES * IN_DIM * 2);   // also y2 region
    unsigned short* axbf = (unsigned short*)alloc((size_t)N_NODES * IN_DIM * 2);
    unsigned short* y1bf = (unsigned short*)alloc((size_t)N_NODES * HID_DIM * 2);
    unsigned short* gbf  = (unsigned short*)alloc((size_t)N_NODES * EMB_DIM * 2);
    float* y2 = (float*)xbf;  // xbf+axbf dead by layer 2; contiguous 25.6 MB
    (void)ws_size; (void)in_sizes; (void)n_in; (void)out_size;

    const int* src  = ei;
    const int* dstp = ei + N_EDGES;

    hipMemsetAsync(ws, 0, zbytes, stream);   // zero fill + stats in one call

    // ELL build: XCD-partitioned scatter, then fused convert (x->bf16, W1t, dinv)
    scatter_xcd<<<NGROUP * BLK_PER_GROUP, 256, 0, stream>>>(src, dstp, fill, col);
    convert_kernel<<<F2B_BLOCKS + TW1_BLOCKS + DINV_BLOCKS, 256, 0, stream>>>(
        x, xbf, W1, W1t, fill, dinv);

    // Layer 1: ax = A x (bf16), y1 = relu(ax@W1 + b1) (bf16) with fused stats1
    aggw_kernel<false, true, false><<<N_NODES / 4, 256, 0, stream>>>(xbf, dinv, fill, col, nullptr, axbf);
    gemm_wres<true, true, HID_DIM, IN_DIM><<<GEMM_BLOCKS, 256, 0, stream>>>(
        axbf, W1t, b1, y1bf, stats, stats + 256, N_NODES);

    // Fold BN1 into W2 (transposed bf16) + pre-aggregation column bias bc2
    prep2_kernel<<<1, 256, 0, stream>>>(stats, stats + 256, gamma1, beta1, W2, W2pt, bc2);

    // Layer 2: g = y1@W2p + bc2 (bf16), y2 = relu(A g + b2) (fp32), stats2
    gemm_wres<false, false, EMB_DIM, HID_DIM><<<GEMM_BLOCKS, 256, 0, stream>>>(
        y1bf, W2pt, bc2, gbf, nullptr, nullptr, N_NODES);
    aggw_kernel<true, false, true><<<N_NODES / 4, 256, 0, stream>>>(gbf, dinv, fill, col, b2, y2);
    stats_fast<EMB_DIM, false><<<256, 256, 0, stream>>>(y2, stats + 512, stats + 640);

    // fused BN2-fold + per-graph segmented max
    segmax_kernel<<<N_GRAPHS, 128, 0, stream>>>(y2, stats + 512, stats + 640,
                                                gamma2, beta2, batch, out);
}

// Round 12
// 358.513 us; speedup vs baseline: 1.0914x; 1.0914x over previous
//
#include <hip/hip_runtime.h>
#include <math.h>

#define N_NODES 50000
#define N_EDGES 800000
#define N_GRAPHS 512
#define IN_DIM 128
#define HID_DIM 256
#define EMB_DIM 128
#define EPS 1e-5f
#define ELLW 64
#define NGROUP 8
#define GROUPN 6250
#define BLK_PER_GROUP 256
#define EPB ((N_EDGES + BLK_PER_GROUP - 1) / BLK_PER_GROUP)
#define F2B_N (N_NODES * IN_DIM / 4)
#define F2B_BLOCKS ((F2B_N + 255) / 256)
#define TW1_BLOCKS ((HID_DIM * IN_DIM + 255) / 256)
#define DINV_BLOCKS ((N_NODES + 255) / 256)

typedef __attribute__((ext_vector_type(8))) short bf16x8;
typedef __attribute__((ext_vector_type(4))) float f32x4;

static __device__ __forceinline__ unsigned short f2b(float f) {
    unsigned u = __float_as_uint(f);
    return (unsigned short)((u + 0x7fffu + ((u >> 16) & 1u)) >> 16);
}
static __device__ __forceinline__ float b2f(unsigned short h) {
    return __uint_as_float(((unsigned)h) << 16);
}

// ---------- ELL build, XCD-partitioned by dst range (blockIdx%8 -> XCD heuristic) ----------
__global__ void __launch_bounds__(256) scatter_xcd(const int* __restrict__ src,
                                                   const int* __restrict__ dst,
                                                   int* __restrict__ fill,
                                                   int* __restrict__ col) {
    int b = blockIdx.x;
    int g = b & 7;
    int bs = b >> 3;
    int lo = g * GROUPN;
    int hi = lo + GROUPN;
    int e_end = min((bs + 1) * EPB, N_EDGES);
    for (int e = bs * EPB + threadIdx.x; e < e_end; e += 256) {
        int d = dst[e];
        if (d >= lo && d < hi) {
            int pos = atomicAdd(&fill[d], 1);
            pos = min(pos, ELLW - 1);
            col[(d << 6) + pos] = src[e];
        }
    }
}

// ---------- fused conversions + dinv ----------
__global__ void convert_kernel(const float* __restrict__ x, unsigned short* __restrict__ xbf,
                               const float* __restrict__ W1, unsigned short* __restrict__ W1t,
                               const int* __restrict__ fill, float* __restrict__ dinv) {
    int b = blockIdx.x;
    if (b < F2B_BLOCKS) {
        int i = b * 256 + threadIdx.x;
        if (i < F2B_N) {
            float4 v = ((const float4*)x)[i];
            ushort4 o;
            o.x = f2b(v.x); o.y = f2b(v.y); o.z = f2b(v.z); o.w = f2b(v.w);
            ((ushort4*)xbf)[i] = o;
        }
    } else if (b < F2B_BLOCKS + TW1_BLOCKS) {
        int j = (b - F2B_BLOCKS) * 256 + threadIdx.x;
        if (j < HID_DIM * IN_DIM) {
            int n = j >> 7;
            int k = j & 127;
            W1t[j] = f2b(W1[k * HID_DIM + n]);
        }
    } else {
        int v = (b - F2B_BLOCKS - TW1_BLOCKS) * 256 + threadIdx.x;
        if (v < N_NODES) dinv[v] = rsqrtf((float)(min(fill[v], ELLW) + 1));
    }
}

// ---------- wave-per-node aggregation over ELL, quarter-wave 16B row gathers ----------
static __device__ __forceinline__ void acc8(float* acc, uint4 r, float w) {
    const unsigned* u = (const unsigned*)&r;
#pragma unroll
    for (int k = 0; k < 4; ++k) {
        float lo = __uint_as_float((u[k] & 0xFFFFu) << 16);
        float hi = __uint_as_float(u[k] & 0xFFFF0000u);
        acc[2 * k]     += w * lo;
        acc[2 * k + 1] += w * hi;
    }
}

template <bool RELU, bool OUT_BF, bool BIAS>
__global__ void __launch_bounds__(256) aggw_kernel(const unsigned short* __restrict__ h,
                                                   const float* __restrict__ dinv,
                                                   const int* __restrict__ deg,
                                                   const int* __restrict__ col,
                                                   const float* __restrict__ bias,
                                                   void* __restrict__ y) {
    int tid = threadIdx.x;
    int lane = tid & 63;
    int wid = tid >> 6;
    int v = blockIdx.x * 4 + wid;
    int g = lane >> 4;
    int p = lane & 15;

    int beg = v << 6;
    int end = beg + min(deg[v], ELLW);
    float acc[8] = {};

    for (int e = beg; e < end; e += 16) {
        int i0 = e + g, i1 = e + 4 + g, i2 = e + 8 + g, i3 = e + 12 + g;
        int c0 = min(i0, end - 1), c1 = min(i1, end - 1);
        int c2 = min(i2, end - 1), c3 = min(i3, end - 1);
        int u0 = col[c0], u1 = col[c1], u2 = col[c2], u3 = col[c3];
        float w0 = (i0 < end) ? dinv[u0] : 0.f;
        float w1 = (i1 < end) ? dinv[u1] : 0.f;
        float w2 = (i2 < end) ? dinv[u2] : 0.f;
        float w3 = (i3 < end) ? dinv[u3] : 0.f;
        uint4 d0 = *(const uint4*)(h + (size_t)u0 * 128 + p * 8);
        uint4 d1 = *(const uint4*)(h + (size_t)u1 * 128 + p * 8);
        uint4 d2 = *(const uint4*)(h + (size_t)u2 * 128 + p * 8);
        uint4 d3 = *(const uint4*)(h + (size_t)u3 * 128 + p * 8);
        acc8(acc, d0, w0);
        acc8(acc, d1, w1);
        acc8(acc, d2, w2);
        acc8(acc, d3, w3);
    }

#pragma unroll
    for (int k = 0; k < 8; ++k) {
        float a = acc[k];
        a += __shfl_xor(a, 16, 64);
        a += __shfl_xor(a, 32, 64);
        acc[k] = a;
    }

    if (g == 0) {
        uint4 selfr = *(const uint4*)(h + (size_t)v * 128 + p * 8);
        const unsigned* su = (const unsigned*)&selfr;
        float dv = dinv[v];
        float dv2 = dv * dv;
        float o[8];
#pragma unroll
        for (int k = 0; k < 4; ++k) {
            float lo = __uint_as_float((su[k] & 0xFFFFu) << 16);
            float hi = __uint_as_float(su[k] & 0xFFFF0000u);
            o[2 * k]     = dv * acc[2 * k]     + lo * dv2;
            o[2 * k + 1] = dv * acc[2 * k + 1] + hi * dv2;
        }
        if (BIAS) {
            float4 bv0 = *(const float4*)&bias[p * 8];
            float4 bv1 = *(const float4*)&bias[p * 8 + 4];
            o[0] += bv0.x; o[1] += bv0.y; o[2] += bv0.z; o[3] += bv0.w;
            o[4] += bv1.x; o[5] += bv1.y; o[6] += bv1.z; o[7] += bv1.w;
        }
        if (RELU) {
#pragma unroll
            for (int k = 0; k < 8; ++k) o[k] = fmaxf(o[k], 0.f);
        }
        if (OUT_BF) {
            uint4 packed;
            unsigned* pu = (unsigned*)&packed;
#pragma unroll
            for (int k = 0; k < 4; ++k)
                pu[k] = (unsigned)f2b(o[2 * k]) | ((unsigned)f2b(o[2 * k + 1]) << 16);
            *(uint4*)((unsigned short*)y + (size_t)v * 128 + p * 8) = packed;
        } else {
            float* yf = (float*)y + (size_t)v * 128 + p * 8;
            *(float4*)yf = make_float4(o[0], o[1], o[2], o[3]);
            *(float4*)(yf + 4) = make_float4(o[4], o[5], o[6], o[7]);
        }
    }
}

// ---------- MFMA bf16 GEMM (R9 64x64 shape, LDT=36 conflict-free) ----------
// C[M,N] = maybe_relu(A[M,K] @ Bt[N,K]^T + bias); optional fused column stats.
template <bool RELU, bool STATS>
__global__ void __launch_bounds__(256) mfma_gemm_kernel(const unsigned short* __restrict__ A,
                                                        const unsigned short* __restrict__ Bt,
                                                        const float* __restrict__ bias,
                                                        unsigned short* __restrict__ C,
                                                        float* __restrict__ sum,
                                                        float* __restrict__ sumsq,
                                                        int M, int N, int K) {
    const int LDT = 36;  // 32 + 4 pad ushorts = 72B stride: 18 dwords, gcd(18,32)=2 -> conflict-free
    __shared__ unsigned short As[64 * LDT];
    __shared__ unsigned short Bs[64 * LDT];
    int tid = threadIdx.x;
    int bm = blockIdx.x * 64;
    int bn = blockIdx.y * 64;
    int lr = tid >> 2;
    int lc = (tid & 3) * 8;
    int lane = tid & 63;
    int w = tid >> 6;
    int wr = (w >> 1) * 32, wc = (w & 1) * 32;
    int l15 = lane & 15, q = lane >> 4;

    f32x4 acc[2][2] = {};
    bool arow_ok = (bm + lr) < M;
    const unsigned short* Aptr = A + (size_t)(bm + lr) * K + lc;
    const unsigned short* Bptr = Bt + (size_t)(bn + lr) * K + lc;

    for (int k0 = 0; k0 < K; k0 += 32) {
        uint4 av = arow_ok ? *(const uint4*)(Aptr + k0) : make_uint4(0u, 0u, 0u, 0u);
        uint4 bv = *(const uint4*)(Bptr + k0);
        *(uint4*)&As[lr * LDT + lc] = av;
        *(uint4*)&Bs[lr * LDT + lc] = bv;
        __syncthreads();
        bf16x8 a0 = *(const bf16x8*)&As[(wr + 0 + l15) * LDT + q * 8];
        bf16x8 a1 = *(const bf16x8*)&As[(wr + 16 + l15) * LDT + q * 8];
        bf16x8 b0 = *(const bf16x8*)&Bs[(wc + 0 + l15) * LDT + q * 8];
        bf16x8 b1 = *(const bf16x8*)&Bs[(wc + 16 + l15) * LDT + q * 8];
        acc[0][0] = __builtin_amdgcn_mfma_f32_16x16x32_bf16(a0, b0, acc[0][0], 0, 0, 0);
        acc[0][1] = __builtin_amdgcn_mfma_f32_16x16x32_bf16(a0, b1, acc[0][1], 0, 0, 0);
        acc[1][0] = __builtin_amdgcn_mfma_f32_16x16x32_bf16(a1, b0, acc[1][0], 0, 0, 0);
        acc[1][1] = __builtin_amdgcn_mfma_f32_16x16x32_bf16(a1, b1, acc[1][1], 0, 0, 0);
        __syncthreads();
    }

#pragma unroll
    for (int ni = 0; ni < 2; ++ni) {
        int colc = bn + wc + ni * 16 + l15;
        float bv = bias ? bias[colc] : 0.f;
        float s = 0.f, sq2 = 0.f;
#pragma unroll
        for (int mi = 0; mi < 2; ++mi) {
#pragma unroll
            for (int r = 0; r < 4; ++r) {
                int row = bm + wr + mi * 16 + q * 4 + r;
                bool ok = row < M;
                float vv = acc[mi][ni][r] + bv;
                if (RELU) vv = fmaxf(vv, 0.f);
                unsigned short us = f2b(vv);
                if (ok) C[(size_t)row * N + colc] = us;
                if (STATS) {
                    float xr = ok ? b2f(us) : 0.f;
                    s += xr;
                    sq2 += xr * xr;
                }
            }
        }
        if (STATS) {
            s += __shfl_xor(s, 16, 64);  s += __shfl_xor(s, 32, 64);
            sq2 += __shfl_xor(sq2, 16, 64); sq2 += __shfl_xor(sq2, 32, 64);
            if (q == 0) {
                atomicAdd(&sum[colc], s);
                atomicAdd(&sumsq[colc], sq2);
            }
        }
    }
}

// ---------- fast per-channel sum/sumsq (for fp32 y2) ----------
template <int C, bool BF>
__global__ void __launch_bounds__(256) stats_fast(const void* __restrict__ yv,
                                                  float* __restrict__ sum,
                                                  float* __restrict__ sumsq) {
    constexpr int VEC = BF ? 8 : 4;
    constexpr int NCHUNK = C / VEC;
    constexpr int ROWS = 256 / NCHUNK;
    constexpr int STRIDE = 256 * ROWS;
    __shared__ float sp[256 * VEC];
    __shared__ float qp[256 * VEC];
    int t = threadIdx.x;
    int j = t & (NCHUNK - 1);
    float s[VEC], q[VEC];
#pragma unroll
    for (int k = 0; k < VEC; ++k) { s[k] = 0.f; q[k] = 0.f; }

    const char* base = (const char*)yv + (size_t)j * 16;
    auto body = [&](int v) {
        uint4 raw = *(const uint4*)(base + (size_t)v * (C * (BF ? 2 : 4)));
        float x[VEC];
        if (BF) {
            const unsigned* u = (const unsigned*)&raw;
#pragma unroll
            for (int k = 0; k < 4; ++k) {
                x[2 * k]     = __uint_as_float((u[k] & 0xFFFFu) << 16);
                x[2 * k + 1] = __uint_as_float(u[k] & 0xFFFF0000u);
            }
        } else {
            const float* f = (const float*)&raw;
#pragma unroll
            for (int k = 0; k < VEC; ++k) x[k] = f[k];
        }
#pragma unroll
        for (int k = 0; k < VEC; ++k) { s[k] += x[k]; q[k] += x[k] * x[k]; }
    };

    int v = blockIdx.x * ROWS + (t >> 5);
    for (; v + 3 * STRIDE < N_NODES; v += 4 * STRIDE) {
        body(v); body(v + STRIDE); body(v + 2 * STRIDE); body(v + 3 * STRIDE);
    }
    for (; v < N_NODES; v += STRIDE) body(v);

#pragma unroll
    for (int k = 0; k < VEC; ++k) { sp[t * VEC + k] = s[k]; qp[t * VEC + k] = q[k]; }
    __syncthreads();
    if (t < C) {
        float ss = 0.f, qq = 0.f;
#pragma unroll
        for (int rr = 0; rr < ROWS; ++rr) {
            ss += sp[rr * (NCHUNK * VEC) + t];
            qq += qp[rr * (NCHUNK * VEC) + t];
        }
        atomicAdd(&sum[t], ss);
        atomicAdd(&sumsq[t], qq);
    }
}

// ---------- fold BN1 into W2 ----------
__global__ void prep2_kernel(const float* __restrict__ sum1, const float* __restrict__ sumsq1,
                             const float* __restrict__ gamma1, const float* __restrict__ beta1,
                             const float* __restrict__ W2, unsigned short* __restrict__ W2pt,
                             float* __restrict__ bc2) {
    __shared__ float a1s[HID_DIM], s1s[HID_DIM];
    int t = threadIdx.x;
    {
        float m = sum1[t] * (1.f / N_NODES);
        float var = sumsq1[t] * (1.f / N_NODES) - m * m;
        float a = gamma1[t] * rsqrtf(var + EPS);
        a1s[t] = a;
        s1s[t] = beta1[t] - m * a;
    }
    __syncthreads();
    if (t < EMB_DIM) {
        float bacc = 0.f;
        for (int k = 0; k < HID_DIM; ++k) {
            float w = W2[k * EMB_DIM + t];
            W2pt[t * HID_DIM + k] = f2b(a1s[k] * w);
            bacc += s1s[k] * w;
        }
        bc2[t] = bacc;
    }
}

// ---------- segmented max per graph (batch sorted), BN2 fold computed in-block ----------
__global__ void __launch_bounds__(128) segmax_kernel(const float* __restrict__ y,
                                                     const float* __restrict__ sum2,
                                                     const float* __restrict__ sumsq2,
                                                     const float* __restrict__ gamma2,
                                                     const float* __restrict__ beta2,
                                                     const int* __restrict__ batch,
                                                     float* __restrict__ out) {
    __shared__ int sh[2];
    int g = blockIdx.x;
    int c = threadIdx.x;
    float mch = sum2[c] * (1.f / N_NODES);
    float var = sumsq2[c] * (1.f / N_NODES) - mch * mch;
    float ac = gamma2[c] * rsqrtf(var + EPS);
    float sc = beta2[c] - mch * ac;
    if (threadIdx.x == 0) {
        int lo = 0, hi = N_NODES;
        while (lo < hi) { int mid = (lo + hi) >> 1; if (batch[mid] < g) lo = mid + 1; else hi = mid; }
        sh[0] = lo;
        hi = N_NODES;
        while (lo < hi) { int mid = (lo + hi) >> 1; if (batch[mid] < g + 1) lo = mid + 1; else hi = mid; }
        sh[1] = lo;
    }
    __syncthreads();
    int beg = sh[0], end = sh[1];
    float m = -INFINITY;
    for (int v = beg; v < end; ++v) {
        m = fmaxf(m, fmaf(ac, y[(size_t)v * EMB_DIM + c], sc));
    }
    out[(size_t)g * EMB_DIM + c] = m;
}

extern "C" void kernel_launch(void* const* d_in, const int* in_sizes, int n_in,
                              void* d_out, int out_size, void* d_ws, size_t ws_size,
                              hipStream_t stream) {
    const float* x      = (const float*)d_in[0];
    const int*   ei     = (const int*)d_in[1];
    const int*   batch  = (const int*)d_in[2];
    const float* W1     = (const float*)d_in[3];
    const float* b1     = (const float*)d_in[4];
    const float* gamma1 = (const float*)d_in[5];
    const float* beta1  = (const float*)d_in[6];
    const float* W2     = (const float*)d_in[7];
    const float* b2     = (const float*)d_in[8];
    const float* gamma2 = (const float*)d_in[9];
    const float* beta2  = (const float*)d_in[10];
    float* out = (float*)d_out;

    char* ws = (char*)d_ws;
    size_t off = 0;
    auto alloc = [&](size_t bytes) -> char* {
        char* p = ws + off;
        off = (off + bytes + 255) & ~(size_t)255;
        return p;
    };
    int*   fill   = (int*)alloc((size_t)N_NODES * 4);
    float* stats  = (float*)alloc(1024 * 4);
    size_t zbytes = off;
    int*   col    = (int*)alloc((size_t)N_NODES * ELLW * 4);
    float* dinv   = (float*)alloc((size_t)N_NODES * 4);
    float* bc2    = (float*)alloc((size_t)EMB_DIM * 4);
    unsigned short* W1t  = (unsigned short*)alloc((size_t)HID_DIM * IN_DIM * 2);
    unsigned short* W2pt = (unsigned short*)alloc((size_t)HID_DIM * EMB_DIM * 2);
    unsigned short* xbf  = (unsigned short*)alloc((size_t)N_NODES * IN_DIM * 2);   // also y2 region
    unsigned short* axbf = (unsigned short*)alloc((size_t)N_NODES * IN_DIM * 2);
    unsigned short* y1bf = (unsigned short*)alloc((size_t)N_NODES * HID_DIM * 2);
    unsigned short* gbf  = (unsigned short*)alloc((size_t)N_NODES * EMB_DIM * 2);
    float* y2 = (float*)xbf;  // xbf+axbf dead by layer 2; contiguous 25.6 MB
    (void)ws_size; (void)in_sizes; (void)n_in; (void)out_size;

    const int* src  = ei;
    const int* dstp = ei + N_EDGES;

    hipMemsetAsync(ws, 0, zbytes, stream);   // zero fill + stats in one call

    // ELL build: XCD-partitioned scatter, then fused convert (x->bf16, W1t, dinv)
    scatter_xcd<<<NGROUP * BLK_PER_GROUP, 256, 0, stream>>>(src, dstp, fill, col);
    convert_kernel<<<F2B_BLOCKS + TW1_BLOCKS + DINV_BLOCKS, 256, 0, stream>>>(
        x, xbf, W1, W1t, fill, dinv);

    // Layer 1: ax = A x (bf16), y1 = relu(ax@W1 + b1) (bf16) with fused stats1
    aggw_kernel<false, true, false><<<N_NODES / 4, 256, 0, stream>>>(xbf, dinv, fill, col, nullptr, axbf);
    dim3 g1((N_NODES + 63) / 64, HID_DIM / 64);
    mfma_gemm_kernel<true, true><<<g1, 256, 0, stream>>>(axbf, W1t, b1, y1bf,
                                                         stats, stats + 256,
                                                         N_NODES, HID_DIM, IN_DIM);

    // Fold BN1 into W2 (transposed bf16) + pre-aggregation column bias bc2
    prep2_kernel<<<1, 256, 0, stream>>>(stats, stats + 256, gamma1, beta1, W2, W2pt, bc2);

    // Layer 2: g = y1@W2p + bc2 (bf16), y2 = relu(A g + b2) (fp32), stats2
    dim3 g2((N_NODES + 63) / 64, EMB_DIM / 64);
    mfma_gemm_kernel<false, false><<<g2, 256, 0, stream>>>(y1bf, W2pt, bc2, gbf,
                                                           nullptr, nullptr,
                                                           N_NODES, EMB_DIM, HID_DIM);
    aggw_kernel<true, false, true><<<N_NODES / 4, 256, 0, stream>>>(gbf, dinv, fill, col, b2, y2);
    stats_fast<EMB_DIM, false><<<256, 256, 0, stream>>>(y2, stats + 512, stats + 640);

    // fused BN2-fold + per-graph segmented max
    segmax_kernel<<<N_GRAPHS, 128, 0, stream>>>(y2, stats + 512, stats + 640,
                                                gamma2, beta2, batch, out);
}

// Round 13
// 302.605 us; speedup vs baseline: 1.2931x; 1.1848x over previous
//
#include <hip/hip_runtime.h>
#include <math.h>

#define N_NODES 50000
#define N_EDGES 800000
#define N_GRAPHS 512
#define IN_DIM 128
#define HID_DIM 256
#define EMB_DIM 128
#define EPS 1e-5f
#define ELLW 64
#define NGROUP 8
#define GROUPN 6250
#define BLK_PER_GROUP 256
#define EPB ((N_EDGES + BLK_PER_GROUP - 1) / BLK_PER_GROUP)
#define F2B_N (N_NODES * IN_DIM / 4)
#define F2B_BLOCKS ((F2B_N + 255) / 256)
#define TW1_BLOCKS ((HID_DIM * IN_DIM + 255) / 256)
#define DINV_BLOCKS ((N_NODES + 255) / 256)

typedef __attribute__((ext_vector_type(8))) short bf16x8;
typedef __attribute__((ext_vector_type(4))) float f32x4;

static __device__ __forceinline__ unsigned short f2b(float f) {
    unsigned u = __float_as_uint(f);
    return (unsigned short)((u + 0x7fffu + ((u >> 16) & 1u)) >> 16);
}
static __device__ __forceinline__ float b2f(unsigned short h) {
    return __uint_as_float(((unsigned)h) << 16);
}

// ---------- ELL build, XCD-partitioned by dst range (blockIdx%8 -> XCD heuristic) ----------
__global__ void __launch_bounds__(256) scatter_xcd(const int* __restrict__ src,
                                                   const int* __restrict__ dst,
                                                   int* __restrict__ fill,
                                                   int* __restrict__ col) {
    int b = blockIdx.x;
    int g = b & 7;
    int bs = b >> 3;
    int lo = g * GROUPN;
    int hi = lo + GROUPN;
    int e_end = min((bs + 1) * EPB, N_EDGES);
    for (int e = bs * EPB + threadIdx.x; e < e_end; e += 256) {
        int d = dst[e];
        if (d >= lo && d < hi) {
            int pos = atomicAdd(&fill[d], 1);
            pos = min(pos, ELLW - 1);
            col[(d << 6) + pos] = src[e];
        }
    }
}

// ---------- fused conversions + dinv ----------
__global__ void convert_kernel(const float* __restrict__ x, unsigned short* __restrict__ xbf,
                               const float* __restrict__ W1, unsigned short* __restrict__ W1t,
                               const int* __restrict__ fill, float* __restrict__ dinv) {
    int b = blockIdx.x;
    if (b < F2B_BLOCKS) {
        int i = b * 256 + threadIdx.x;
        if (i < F2B_N) {
            float4 v = ((const float4*)x)[i];
            ushort4 o;
            o.x = f2b(v.x); o.y = f2b(v.y); o.z = f2b(v.z); o.w = f2b(v.w);
            ((ushort4*)xbf)[i] = o;
        }
    } else if (b < F2B_BLOCKS + TW1_BLOCKS) {
        int j = (b - F2B_BLOCKS) * 256 + threadIdx.x;
        if (j < HID_DIM * IN_DIM) {
            int n = j >> 7;
            int k = j & 127;
            W1t[j] = f2b(W1[k * HID_DIM + n]);
        }
    } else {
        int v = (b - F2B_BLOCKS - TW1_BLOCKS) * 256 + threadIdx.x;
        if (v < N_NODES) dinv[v] = rsqrtf((float)(min(fill[v], ELLW) + 1));
    }
}

// ---------- wave-per-node aggregation over ELL, quarter-wave 16B row gathers ----------
static __device__ __forceinline__ void acc8(float* acc, uint4 r, float w) {
    const unsigned* u = (const unsigned*)&r;
#pragma unroll
    for (int k = 0; k < 4; ++k) {
        float lo = __uint_as_float((u[k] & 0xFFFFu) << 16);
        float hi = __uint_as_float(u[k] & 0xFFFF0000u);
        acc[2 * k]     += w * lo;
        acc[2 * k + 1] += w * hi;
    }
}

template <bool RELU, bool OUT_BF, bool BIAS>
__global__ void __launch_bounds__(256) aggw_kernel(const unsigned short* __restrict__ h,
                                                   const float* __restrict__ dinv,
                                                   const int* __restrict__ deg,
                                                   const int* __restrict__ col,
                                                   const float* __restrict__ bias,
                                                   void* __restrict__ y) {
    int tid = threadIdx.x;
    int lane = tid & 63;
    int wid = tid >> 6;
    int v = blockIdx.x * 4 + wid;
    int g = lane >> 4;
    int p = lane & 15;

    int beg = v << 6;
    int end = beg + min(deg[v], ELLW);
    float acc[8] = {};

    for (int e = beg; e < end; e += 16) {
        int i0 = e + g, i1 = e + 4 + g, i2 = e + 8 + g, i3 = e + 12 + g;
        int c0 = min(i0, end - 1), c1 = min(i1, end - 1);
        int c2 = min(i2, end - 1), c3 = min(i3, end - 1);
        int u0 = col[c0], u1 = col[c1], u2 = col[c2], u3 = col[c3];
        float w0 = (i0 < end) ? dinv[u0] : 0.f;
        float w1 = (i1 < end) ? dinv[u1] : 0.f;
        float w2 = (i2 < end) ? dinv[u2] : 0.f;
        float w3 = (i3 < end) ? dinv[u3] : 0.f;
        uint4 d0 = *(const uint4*)(h + (size_t)u0 * 128 + p * 8);
        uint4 d1 = *(const uint4*)(h + (size_t)u1 * 128 + p * 8);
        uint4 d2 = *(const uint4*)(h + (size_t)u2 * 128 + p * 8);
        uint4 d3 = *(const uint4*)(h + (size_t)u3 * 128 + p * 8);
        acc8(acc, d0, w0);
        acc8(acc, d1, w1);
        acc8(acc, d2, w2);
        acc8(acc, d3, w3);
    }

#pragma unroll
    for (int k = 0; k < 8; ++k) {
        float a = acc[k];
        a += __shfl_xor(a, 16, 64);
        a += __shfl_xor(a, 32, 64);
        acc[k] = a;
    }

    if (g == 0) {
        uint4 selfr = *(const uint4*)(h + (size_t)v * 128 + p * 8);
        const unsigned* su = (const unsigned*)&selfr;
        float dv = dinv[v];
        float dv2 = dv * dv;
        float o[8];
#pragma unroll
        for (int k = 0; k < 4; ++k) {
            float lo = __uint_as_float((su[k] & 0xFFFFu) << 16);
            float hi = __uint_as_float(su[k] & 0xFFFF0000u);
            o[2 * k]     = dv * acc[2 * k]     + lo * dv2;
            o[2 * k + 1] = dv * acc[2 * k + 1] + hi * dv2;
        }
        if (BIAS) {
            float4 bv0 = *(const float4*)&bias[p * 8];
            float4 bv1 = *(const float4*)&bias[p * 8 + 4];
            o[0] += bv0.x; o[1] += bv0.y; o[2] += bv0.z; o[3] += bv0.w;
            o[4] += bv1.x; o[5] += bv1.y; o[6] += bv1.z; o[7] += bv1.w;
        }
        if (RELU) {
#pragma unroll
            for (int k = 0; k < 8; ++k) o[k] = fmaxf(o[k], 0.f);
        }
        if (OUT_BF) {
            uint4 packed;
            unsigned* pu = (unsigned*)&packed;
#pragma unroll
            for (int k = 0; k < 4; ++k)
                pu[k] = (unsigned)f2b(o[2 * k]) | ((unsigned)f2b(o[2 * k + 1]) << 16);
            *(uint4*)((unsigned short*)y + (size_t)v * 128 + p * 8) = packed;
        } else {
            float* yf = (float*)y + (size_t)v * 128 + p * 8;
            *(float4*)yf = make_float4(o[0], o[1], o[2], o[3]);
            *(float4*)(yf + 4) = make_float4(o[4], o[5], o[6], o[7]);
        }
    }
}

// ---------- MFMA bf16 GEMM (R8 known-good: 64x64, LDT=40) ----------
// C[M,N] = maybe_relu(A[M,K] @ Bt[N,K]^T + bias[N])
template <bool RELU>
__global__ void __launch_bounds__(256) mfma_gemm_kernel(const unsigned short* __restrict__ A,
                                                        const unsigned short* __restrict__ Bt,
                                                        const float* __restrict__ bias,
                                                        unsigned short* __restrict__ C,
                                                        int M, int N, int K) {
    const int LDT = 40;  // 32 + 8 pad (ushorts)
    __shared__ unsigned short As[64 * LDT];
    __shared__ unsigned short Bs[64 * LDT];
    int tid = threadIdx.x;
    int bm = blockIdx.x * 64;
    int bn = blockIdx.y * 64;
    int lr = tid >> 2;
    int lc = (tid & 3) * 8;
    int lane = tid & 63;
    int w = tid >> 6;
    int wr = (w >> 1) * 32, wc = (w & 1) * 32;
    int l15 = lane & 15, q = lane >> 4;

    f32x4 acc[2][2] = {};
    bool arow_ok = (bm + lr) < M;
    const unsigned short* Aptr = A + (size_t)(bm + lr) * K + lc;
    const unsigned short* Bptr = Bt + (size_t)(bn + lr) * K + lc;

    for (int k0 = 0; k0 < K; k0 += 32) {
        uint4 av = arow_ok ? *(const uint4*)(Aptr + k0) : make_uint4(0u, 0u, 0u, 0u);
        uint4 bv = *(const uint4*)(Bptr + k0);
        *(uint4*)&As[lr * LDT + lc] = av;
        *(uint4*)&Bs[lr * LDT + lc] = bv;
        __syncthreads();
        bf16x8 a0 = *(const bf16x8*)&As[(wr + 0 + l15) * LDT + q * 8];
        bf16x8 a1 = *(const bf16x8*)&As[(wr + 16 + l15) * LDT + q * 8];
        bf16x8 b0 = *(const bf16x8*)&Bs[(wc + 0 + l15) * LDT + q * 8];
        bf16x8 b1 = *(const bf16x8*)&Bs[(wc + 16 + l15) * LDT + q * 8];
        acc[0][0] = __builtin_amdgcn_mfma_f32_16x16x32_bf16(a0, b0, acc[0][0], 0, 0, 0);
        acc[0][1] = __builtin_amdgcn_mfma_f32_16x16x32_bf16(a0, b1, acc[0][1], 0, 0, 0);
        acc[1][0] = __builtin_amdgcn_mfma_f32_16x16x32_bf16(a1, b0, acc[1][0], 0, 0, 0);
        acc[1][1] = __builtin_amdgcn_mfma_f32_16x16x32_bf16(a1, b1, acc[1][1], 0, 0, 0);
        __syncthreads();
    }

#pragma unroll
    for (int mi = 0; mi < 2; ++mi)
#pragma unroll
        for (int ni = 0; ni < 2; ++ni) {
            int colc = bn + wc + ni * 16 + l15;
            float bv = bias ? bias[colc] : 0.f;
#pragma unroll
            for (int r = 0; r < 4; ++r) {
                int row = bm + wr + mi * 16 + q * 4 + r;
                if (row < M) {
                    float vv = acc[mi][ni][r] + bv;
                    if (RELU) vv = fmaxf(vv, 0.f);
                    C[(size_t)row * N + colc] = f2b(vv);
                }
            }
        }
}

// ---------- fast per-channel sum/sumsq ----------
template <int C, bool BF>
__global__ void __launch_bounds__(256) stats_fast(const void* __restrict__ yv,
                                                  float* __restrict__ sum,
                                                  float* __restrict__ sumsq) {
    constexpr int VEC = BF ? 8 : 4;
    constexpr int NCHUNK = C / VEC;
    constexpr int ROWS = 256 / NCHUNK;
    constexpr int STRIDE = 256 * ROWS;
    __shared__ float sp[256 * VEC];
    __shared__ float qp[256 * VEC];
    int t = threadIdx.x;
    int j = t & (NCHUNK - 1);
    float s[VEC], q[VEC];
#pragma unroll
    for (int k = 0; k < VEC; ++k) { s[k] = 0.f; q[k] = 0.f; }

    const char* base = (const char*)yv + (size_t)j * 16;
    auto body = [&](int v) {
        uint4 raw = *(const uint4*)(base + (size_t)v * (C * (BF ? 2 : 4)));
        float x[VEC];
        if (BF) {
            const unsigned* u = (const unsigned*)&raw;
#pragma unroll
            for (int k = 0; k < 4; ++k) {
                x[2 * k]     = __uint_as_float((u[k] & 0xFFFFu) << 16);
                x[2 * k + 1] = __uint_as_float(u[k] & 0xFFFF0000u);
            }
        } else {
            const float* f = (const float*)&raw;
#pragma unroll
            for (int k = 0; k < VEC; ++k) x[k] = f[k];
        }
#pragma unroll
        for (int k = 0; k < VEC; ++k) { s[k] += x[k]; q[k] += x[k] * x[k]; }
    };

    int v = blockIdx.x * ROWS + (t >> 5);
    for (; v + 3 * STRIDE < N_NODES; v += 4 * STRIDE) {
        body(v); body(v + STRIDE); body(v + 2 * STRIDE); body(v + 3 * STRIDE);
    }
    for (; v < N_NODES; v += STRIDE) body(v);

#pragma unroll
    for (int k = 0; k < VEC; ++k) { sp[t * VEC + k] = s[k]; qp[t * VEC + k] = q[k]; }
    __syncthreads();
    if (t < C) {
        float ss = 0.f, qq = 0.f;
#pragma unroll
        for (int rr = 0; rr < ROWS; ++rr) {
            ss += sp[rr * (NCHUNK * VEC) + t];
            qq += qp[rr * (NCHUNK * VEC) + t];
        }
        atomicAdd(&sum[t], ss);
        atomicAdd(&sumsq[t], qq);
    }
}

// ---------- fold BN1 into W2 ----------
__global__ void prep2_kernel(const float* __restrict__ sum1, const float* __restrict__ sumsq1,
                             const float* __restrict__ gamma1, const float* __restrict__ beta1,
                             const float* __restrict__ W2, unsigned short* __restrict__ W2pt,
                             float* __restrict__ bc2) {
    __shared__ float a1s[HID_DIM], s1s[HID_DIM];
    int t = threadIdx.x;
    {
        float m = sum1[t] * (1.f / N_NODES);
        float var = sumsq1[t] * (1.f / N_NODES) - m * m;
        float a = gamma1[t] * rsqrtf(var + EPS);
        a1s[t] = a;
        s1s[t] = beta1[t] - m * a;
    }
    __syncthreads();
    if (t < EMB_DIM) {
        float bacc = 0.f;
        for (int k = 0; k < HID_DIM; ++k) {
            float w = W2[k * EMB_DIM + t];
            W2pt[t * HID_DIM + k] = f2b(a1s[k] * w);
            bacc += s1s[k] * w;
        }
        bc2[t] = bacc;
    }
}

// ---------- segmented max per graph (batch sorted), BN2 fold computed in-block ----------
__global__ void __launch_bounds__(128) segmax_kernel(const float* __restrict__ y,
                                                     const float* __restrict__ sum2,
                                                     const float* __restrict__ sumsq2,
                                                     const float* __restrict__ gamma2,
                                                     const float* __restrict__ beta2,
                                                     const int* __restrict__ batch,
                                                     float* __restrict__ out) {
    __shared__ int sh[2];
    int g = blockIdx.x;
    int c = threadIdx.x;
    float mch = sum2[c] * (1.f / N_NODES);
    float var = sumsq2[c] * (1.f / N_NODES) - mch * mch;
    float ac = gamma2[c] * rsqrtf(var + EPS);
    float sc = beta2[c] - mch * ac;
    if (threadIdx.x == 0) {
        int lo = 0, hi = N_NODES;
        while (lo < hi) { int mid = (lo + hi) >> 1; if (batch[mid] < g) lo = mid + 1; else hi = mid; }
        sh[0] = lo;
        hi = N_NODES;
        while (lo < hi) { int mid = (lo + hi) >> 1; if (batch[mid] < g + 1) lo = mid + 1; else hi = mid; }
        sh[1] = lo;
    }
    __syncthreads();
    int beg = sh[0], end = sh[1];
    float m = -INFINITY;
    for (int v = beg; v < end; ++v) {
        m = fmaxf(m, fmaf(ac, y[(size_t)v * EMB_DIM + c], sc));
    }
    out[(size_t)g * EMB_DIM + c] = m;
}

extern "C" void kernel_launch(void* const* d_in, const int* in_sizes, int n_in,
                              void* d_out, int out_size, void* d_ws, size_t ws_size,
                              hipStream_t stream) {
    const float* x      = (const float*)d_in[0];
    const int*   ei     = (const int*)d_in[1];
    const int*   batch  = (const int*)d_in[2];
    const float* W1     = (const float*)d_in[3];
    const float* b1     = (const float*)d_in[4];
    const float* gamma1 = (const float*)d_in[5];
    const float* beta1  = (const float*)d_in[6];
    const float* W2     = (const float*)d_in[7];
    const float* b2     = (const float*)d_in[8];
    const float* gamma2 = (const float*)d_in[9];
    const float* beta2  = (const float*)d_in[10];
    float* out = (float*)d_out;

    char* ws = (char*)d_ws;
    size_t off = 0;
    auto alloc = [&](size_t bytes) -> char* {
        char* p = ws + off;
        off = (off + bytes + 255) & ~(size_t)255;
        return p;
    };
    int*   fill   = (int*)alloc((size_t)N_NODES * 4);
    float* stats  = (float*)alloc(1024 * 4);
    size_t zbytes = off;
    int*   col    = (int*)alloc((size_t)N_NODES * ELLW * 4);
    float* dinv   = (float*)alloc((size_t)N_NODES * 4);
    float* bc2    = (float*)alloc((size_t)EMB_DIM * 4);
    unsigned short* W1t  = (unsigned short*)alloc((size_t)HID_DIM * IN_DIM * 2);
    unsigned short* W2pt = (unsigned short*)alloc((size_t)HID_DIM * EMB_DIM * 2);
    unsigned short* xbf  = (unsigned short*)alloc((size_t)N_NODES * IN_DIM * 2);   // also y2 region
    unsigned short* axbf = (unsigned short*)alloc((size_t)N_NODES * IN_DIM * 2);
    unsigned short* y1bf = (unsigned short*)alloc((size_t)N_NODES * HID_DIM * 2);
    unsigned short* gbf  = (unsigned short*)alloc((size_t)N_NODES * EMB_DIM * 2);
    float* y2 = (float*)xbf;  // xbf+axbf dead by layer 2; contiguous 25.6 MB
    (void)ws_size; (void)in_sizes; (void)n_in; (void)out_size;

    const int* src  = ei;
    const int* dstp = ei + N_EDGES;

    hipMemsetAsync(ws, 0, zbytes, stream);   // zero fill + stats in one call

    // ELL build: XCD-partitioned scatter, then fused convert (x->bf16, W1t, dinv)
    scatter_xcd<<<NGROUP * BLK_PER_GROUP, 256, 0, stream>>>(src, dstp, fill, col);
    convert_kernel<<<F2B_BLOCKS + TW1_BLOCKS + DINV_BLOCKS, 256, 0, stream>>>(
        x, xbf, W1, W1t, fill, dinv);

    // Layer 1: ax = A x (bf16), y1 = relu(ax@W1 + b1) (bf16), stats
    aggw_kernel<false, true, false><<<N_NODES / 4, 256, 0, stream>>>(xbf, dinv, fill, col, nullptr, axbf);
    dim3 g1((N_NODES + 63) / 64, HID_DIM / 64);
    mfma_gemm_kernel<true><<<g1, 256, 0, stream>>>(axbf, W1t, b1, y1bf, N_NODES, HID_DIM, IN_DIM);
    stats_fast<HID_DIM, true><<<256, 256, 0, stream>>>(y1bf, stats, stats + 256);

    // Fold BN1 into W2 (transposed bf16) + pre-aggregation column bias bc2
    prep2_kernel<<<1, 256, 0, stream>>>(stats, stats + 256, gamma1, beta1, W2, W2pt, bc2);

    // Layer 2: g = y1@W2p + bc2 (bf16), y2 = relu(A g + b2) (fp32), stats2
    dim3 g2((N_NODES + 63) / 64, EMB_DIM / 64);
    mfma_gemm_kernel<false><<<g2, 256, 0, stream>>>(y1bf, W2pt, bc2, gbf,
                                                    N_NODES, EMB_DIM, HID_DIM);
    aggw_kernel<true, false, true><<<N_NODES / 4, 256, 0, stream>>>(gbf, dinv, fill, col, b2, y2);
    stats_fast<EMB_DIM, false><<<256, 256, 0, stream>>>(y2, stats + 512, stats + 640);

    // fused BN2-fold + per-graph segmented max
    segmax_kernel<<<N_GRAPHS, 128, 0, stream>>>(y2, stats + 512, stats + 640,
                                                gamma2, beta2, batch, out);
}